// Round 1
// baseline (1197.679 us; speedup 1.0000x reference)
//
#include <hip/hip_runtime.h>
#include <hip/hip_bf16.h>
#include <cstdint>
#include <cstddef>

#define A_REAL 50000
#define A_PAD  50048      // 391 * 128
#define MTILES 391
#define NBOND  6
#define HD     512
#define FATOM  133
#define FBOND  14
#define KWI    160        // 133 padded to mult of 32
#define KWH    544        // 512+14 padded
#define KWO    672        // 512+133 padded
#define NMOL   2000
#define MOLPAD 2048
#define APM    25
#define NHID   256

typedef __bf16 bf16x8 __attribute__((ext_vector_type(8)));
typedef float  f32x4  __attribute__((ext_vector_type(4)));
typedef short  short8 __attribute__((ext_vector_type(8)));

__device__ __forceinline__ float b2f(unsigned short u) {
  return __uint_as_float(((unsigned int)u) << 16);
}
__device__ __forceinline__ unsigned short f2b(float f) {
  unsigned int x = __float_as_uint(f);
  unsigned int r = (x + 0x7fffu + ((x >> 16) & 1u)) >> 16;
  return (unsigned short)r;
}

// ---------------- zero the pad regions (every call, deterministic) -----------
__global__ void zero_pads(unsigned short* __restrict__ wNei,
                          unsigned short* __restrict__ wWoIn,
                          unsigned short* __restrict__ wEnc)
{
  const int t = blockIdx.x * 256 + threadIdx.x;
  if (t < 48 * KWH)  wNei [(size_t)A_REAL * KWH  + t] = 0;
  if (t < 48 * KWO)  wWoIn[(size_t)A_REAL * KWO  + t] = 0;
  if (t < 48 * 1024) wEnc [(size_t)NMOL  * 1024  + t] = 0;
}

// ---------------- f32 weights -> padded bf16 ---------------------------------
// mode 0: plain pad.  mode 1: Wo reorder (src [512][645] = [f_atoms|a_msg] ->
// dst cols 0..511 = a_msg part, 512..644 = f_atoms part, rest 0)
__global__ void convw(unsigned short* __restrict__ dst, const float* __restrict__ src,
                      int Ksrc, int ldd, int rows, int mode)
{
  const int idx = blockIdx.x * 256 + threadIdx.x;
  if (idx >= rows * ldd) return;
  const int n = idx / ldd, k = idx % ldd;
  float v = 0.f;
  if (mode == 0) {
    if (k < Ksrc) v = src[(size_t)n * Ksrc + k];
  } else {
    if (k < 512)      v = src[(size_t)n * 645 + 133 + k];
    else if (k < 645) v = src[(size_t)n * 645 + (k - 512)];
  }
  dst[(size_t)n * ldd + k] = f2b(v);
}

// ---------------- f_atoms -> wWoIn cols 512..671 (bf16, padded) --------------
__global__ void atoms_prep(unsigned short* __restrict__ wWoIn, const float* __restrict__ f_atoms)
{
  const int idx = blockIdx.x * 256 + threadIdx.x;
  if (idx >= A_PAD * KWI) return;
  const int r = idx / KWI, c = idx % KWI;
  float v = 0.f;
  if (r < A_REAL && c < FATOM) v = f_atoms[(size_t)r * FATOM + c];
  wWoIn[(size_t)r * KWO + 512 + c] = f2b(v);
}

// ---------------- bond gather-sum -> wNei cols 512..543 (once per side) ------
__global__ void bond_gather(unsigned short* __restrict__ wNei, const float* __restrict__ f_bonds,
                            const int* __restrict__ a2b)
{
  const int a = blockIdx.x * 256 + threadIdx.x;
  if (a >= A_REAL) return;
  float acc[FBOND];
  #pragma unroll
  for (int c = 0; c < FBOND; ++c) acc[c] = 0.f;
  #pragma unroll
  for (int j = 0; j < NBOND; ++j) {
    const int b = a2b[a * NBOND + j];
    const float* row = f_bonds + (size_t)b * FBOND;
    #pragma unroll
    for (int c = 0; c < FBOND; ++c) acc[c] += row[c];
  }
  unsigned short* d = wNei + (size_t)a * KWH + 512;
  #pragma unroll
  for (int c = 0; c < FBOND; ++c) d[c] = f2b(acc[c]);
  #pragma unroll
  for (int c = FBOND; c < 32; ++c) d[c] = 0;   // zero pad cols 526..543
}

// ---------------- 6-neighbor gather-sum of msg -> dst cols 0..511 ------------
__launch_bounds__(256)
__global__ void gather6(unsigned short* __restrict__ dst, int dstLd,
                        const unsigned short* __restrict__ msg,
                        const int* __restrict__ a2a)
{
  const int a    = blockIdx.x * 4 + (threadIdx.x >> 6);
  const int lane = threadIdx.x & 63;
  const int* idx = a2a + a * NBOND;
  float acc[8] = {0.f,0.f,0.f,0.f,0.f,0.f,0.f,0.f};
  #pragma unroll
  for (int j = 0; j < NBOND; ++j) {
    const int r = idx[j];
    short8 v = *reinterpret_cast<const short8*>(msg + (size_t)r * HD + lane * 8);
    #pragma unroll
    for (int e = 0; e < 8; ++e) acc[e] += b2f((unsigned short)v[e]);
  }
  short8 o;
  #pragma unroll
  for (int e = 0; e < 8; ++e) o[e] = (short)f2b(acc[e]);
  *reinterpret_cast<short8*>(dst + (size_t)a * dstLd + lane * 8) = o;
}

// ---------------- bf16 MFMA GEMM, m97 structure ------------------------------
// C[M x 512or256] = A[M x K] * W[N x K]^T  (all bf16, fp32 accum)
// 128x128 tile, BK=32, 256 thr / 4 waves, global_load_lds width-16 staging.
// MODE 0 (Wi): outA=x (bias only), outB=msg=relu(x)
// MODE 1 (Wh): outB=x (read), outA=msg=relu(x + acc + bias)
// MODE 2 (Wo/FFN1): outA = relu(acc + bias)
template<int MODE>
__launch_bounds__(256)
__global__ void gemm_bf16(const unsigned short* __restrict__ A, int lda,
                          const unsigned short* __restrict__ W, int ldb,
                          const float* __restrict__ bias, int K,
                          unsigned short* __restrict__ outA,
                          unsigned short* __restrict__ outB,
                          int outLd)
{
  __shared__ alignas(16) unsigned short lA[128 * 32];
  __shared__ alignas(16) unsigned short lB[128 * 32];
  const int tid  = threadIdx.x;
  const int wav  = tid >> 6;
  const int lane = tid & 63;
  const int wm = wav >> 1, wn = wav & 1;
  const size_t tileM = (size_t)blockIdx.x * 128;
  const int n0 = blockIdx.y * 128;

  const int srow = lane >> 2;          // staging: row within 16-row chunk
  const int scol = (lane & 3) * 8;     // staging: col (bf16) within 32
  const int fr = lane & 15;            // fragment row/col
  const int fk = (lane >> 4) * 8;      // fragment k base

  f32x4 acc[4][4];
  #pragma unroll
  for (int m = 0; m < 4; ++m)
    #pragma unroll
    for (int n = 0; n < 4; ++n)
      acc[m][n] = (f32x4){0.f, 0.f, 0.f, 0.f};

  const unsigned short* Abase = A + tileM * (size_t)lda;
  const unsigned short* Wbase = W + (size_t)n0 * (size_t)ldb;

  for (int k0 = 0; k0 < K; k0 += 32) {
    #pragma unroll
    for (int i = 0; i < 2; ++i) {
      const int c = i * 4 + wav;            // chunk 0..7, 1024B each
      const int r = c * 16 + srow;          // tile row 0..127
      const unsigned short* ga = Abase + (size_t)r * lda + (k0 + scol);
      const unsigned short* gb = Wbase + (size_t)r * ldb + (k0 + scol);
      __builtin_amdgcn_global_load_lds(
          (const __attribute__((address_space(1))) unsigned int*)ga,
          (__attribute__((address_space(3))) unsigned int*)&lA[c * 512], 16, 0, 0);
      __builtin_amdgcn_global_load_lds(
          (const __attribute__((address_space(1))) unsigned int*)gb,
          (__attribute__((address_space(3))) unsigned int*)&lB[c * 512], 16, 0, 0);
    }
    __syncthreads();
    bf16x8 af[4], bfm[4];
    #pragma unroll
    for (int m = 0; m < 4; ++m)
      af[m] = *reinterpret_cast<const bf16x8*>(&lA[(wm * 64 + m * 16 + fr) * 32 + fk]);
    #pragma unroll
    for (int n = 0; n < 4; ++n)
      bfm[n] = *reinterpret_cast<const bf16x8*>(&lB[(wn * 64 + n * 16 + fr) * 32 + fk]);
    #pragma unroll
    for (int m = 0; m < 4; ++m)
      #pragma unroll
      for (int n = 0; n < 4; ++n)
        acc[m][n] = __builtin_amdgcn_mfma_f32_16x16x32_bf16(af[m], bfm[n], acc[m][n], 0, 0, 0);
    __syncthreads();
  }

  const int rb = (lane >> 4) * 4;
  const int cI = lane & 15;
  #pragma unroll
  for (int m = 0; m < 4; ++m) {
    #pragma unroll
    for (int n = 0; n < 4; ++n) {
      const int colg = n0 + wn * 64 + n * 16 + cI;
      const float bv = bias[colg];
      #pragma unroll
      for (int i = 0; i < 4; ++i) {
        const size_t rowg = tileM + wm * 64 + m * 16 + rb + i;
        float v = acc[m][n][i] + bv;
        const size_t off = rowg * (size_t)outLd + colg;
        if (MODE == 0) {
          outA[off] = f2b(v);
          outB[off] = f2b(fmaxf(v, 0.f));
        } else if (MODE == 1) {
          v += b2f(outB[off]);
          outA[off] = f2b(fmaxf(v, 0.f));
        } else {
          outA[off] = f2b(fmaxf(v, 0.f));
        }
      }
    }
  }
}

// ---------------- per-molecule mean over 25 atoms -> enc (bf16) --------------
__launch_bounds__(256)
__global__ void readout(const unsigned short* __restrict__ h, unsigned short* __restrict__ enc)
{
  const int mol = blockIdx.x;
  const int t = threadIdx.x;               // cols 2t, 2t+1
  const unsigned short* base = h + (size_t)mol * APM * HD + t * 2;
  float s0 = 0.f, s1 = 0.f;
  #pragma unroll
  for (int r = 0; r < APM; ++r) {
    unsigned int v = *reinterpret_cast<const unsigned int*>(base + (size_t)r * HD);
    s0 += b2f((unsigned short)(v & 0xffffu));
    s1 += b2f((unsigned short)(v >> 16));
  }
  s0 *= (1.f / 25.f);
  s1 *= (1.f / 25.f);
  unsigned int o = (unsigned int)f2b(s0) | ((unsigned int)f2b(s1) << 16);
  *reinterpret_cast<unsigned int*>(enc + (size_t)mol * 1024 + t * 2) = o;
}

// ---------------- final dot with ffn2 ----------------------------------------
__launch_bounds__(256)
__global__ void ffn2_red(const unsigned short* __restrict__ ff1, const float* __restrict__ w2,
                         const float* __restrict__ b2, float* __restrict__ out)
{
  __shared__ float red[256];
  const int mol = blockIdx.x, t = threadIdx.x;
  red[t] = b2f(ff1[(size_t)mol * NHID + t]) * w2[t];
  __syncthreads();
  #pragma unroll
  for (int s = 128; s > 0; s >>= 1) {
    if (t < s) red[t] += red[t + s];
    __syncthreads();
  }
  if (t == 0) out[mol] = red[0] + b2[0];
}

// -----------------------------------------------------------------------------
extern "C" void kernel_launch(void* const* d_in, const int* in_sizes, int n_in,
                              void* d_out, int out_size, void* d_ws, size_t ws_size,
                              hipStream_t stream)
{
  (void)in_sizes; (void)n_in; (void)out_size; (void)ws_size;
  unsigned char* p = (unsigned char*)d_ws;
  auto take = [&](size_t bytes) -> unsigned short* {
    unsigned short* r = (unsigned short*)p;
    p += (bytes + 1023) & ~(size_t)1023;
    return r;
  };
  unsigned short* wX    = take((size_t)A_PAD * HD  * 2);   // x  (bf16)
  unsigned short* wMsg  = take((size_t)A_PAD * HD  * 2);   // msg (bf16)
  unsigned short* wNei  = take((size_t)A_PAD * KWH * 2);   // nei / (alias) h
  unsigned short* wH    = wNei;
  unsigned short* wWoIn = take((size_t)A_PAD * KWO * 2);   // [a_msg | f_atoms | pad]
  unsigned short* wEnc  = take((size_t)MOLPAD * 1024 * 2); // bf16 [2048][1024]
  unsigned short* wFF1  = take((size_t)MOLPAD * NHID * 2);
  unsigned short* wWiB  = take((size_t)512 * KWI * 2);
  unsigned short* wWhB  = take((size_t)512 * KWH * 2);
  unsigned short* wWoB  = take((size_t)512 * KWO * 2);
  unsigned short* wF1B  = take((size_t)NHID * 1024 * 2);

  zero_pads<<<192, 256, 0, stream>>>(wNei, wWoIn, wEnc);

  for (int side = 0; side < 2; ++side) {
    const float* f_atoms = (const float*)d_in[side * 10 + 0];
    const float* f_bonds = (const float*)d_in[side * 10 + 1];
    const int*   a2a     = (const int*)  d_in[side * 10 + 2];
    const int*   a2b     = (const int*)  d_in[side * 10 + 3];
    const float* Wi_w    = (const float*)d_in[side * 10 + 4];
    const float* Wi_b    = (const float*)d_in[side * 10 + 5];
    const float* Wh_w    = (const float*)d_in[side * 10 + 6];
    const float* Wh_b    = (const float*)d_in[side * 10 + 7];
    const float* Wo_w    = (const float*)d_in[side * 10 + 8];
    const float* Wo_b    = (const float*)d_in[side * 10 + 9];

    convw<<<(512 * KWI) / 256, 256, 0, stream>>>(wWiB, Wi_w, FATOM, KWI, 512, 0);
    convw<<<(512 * KWH) / 256, 256, 0, stream>>>(wWhB, Wh_w, 526, KWH, 512, 0);
    convw<<<(512 * KWO) / 256, 256, 0, stream>>>(wWoB, Wo_w, 645, KWO, 512, 1);
    atoms_prep<<<(A_PAD * KWI) / 256, 256, 0, stream>>>(wWoIn, f_atoms);
    bond_gather<<<(A_REAL + 255) / 256, 256, 0, stream>>>(wNei, f_bonds, a2b);

    // x = f_atoms @ Wi^T + b ; msg = relu(x)   (A read from wWoIn cols 512..671)
    gemm_bf16<0><<<dim3(MTILES, 4), 256, 0, stream>>>(wWoIn + 512, KWO, wWiB, KWI,
                                                      Wi_b, KWI, wX, wMsg, HD);
    for (int it = 0; it < 3; ++it) {
      gather6<<<A_REAL / 4, 256, 0, stream>>>(wNei, KWH, wMsg, a2a);
      gemm_bf16<1><<<dim3(MTILES, 4), 256, 0, stream>>>(wNei, KWH, wWhB, KWH,
                                                        Wh_b, KWH, wMsg, wX, HD);
    }
    gather6<<<A_REAL / 4, 256, 0, stream>>>(wWoIn, KWO, wMsg, a2a);
    gemm_bf16<2><<<dim3(MTILES, 4), 256, 0, stream>>>(wWoIn, KWO, wWoB, KWO,
                                                      Wo_b, KWO, wH, nullptr, HD);
    readout<<<NMOL, 256, 0, stream>>>(wH, wEnc + side * HD);
  }

  const float* ffn1_w = (const float*)d_in[20];
  const float* ffn1_b = (const float*)d_in[21];
  const float* ffn2_w = (const float*)d_in[22];
  const float* ffn2_b = (const float*)d_in[23];

  convw<<<(NHID * 1024) / 256, 256, 0, stream>>>(wF1B, ffn1_w, 1024, 1024, NHID, 0);
  gemm_bf16<2><<<dim3(MOLPAD / 128, NHID / 128), 256, 0, stream>>>(wEnc, 1024, wF1B, 1024,
                                                                   ffn1_b, 1024, wFF1,
                                                                   nullptr, NHID);
  ffn2_red<<<NMOL, 256, 0, stream>>>(wFF1, ffn2_w, ffn2_b, (float*)d_out);
}